// Round 10
// baseline (672.249 us; speedup 1.0000x reference)
//
#include <hip/hip_runtime.h>
#include <math.h>

#define N_VOX (96*96*96)        // 884736 voxels per volume
#define NVOL 8                  // 4 pred + 4 target volumes
#define NEL (4*N_VOX)           // 3538944 elements in pred/target
#define PLANE (96*96)           // 9216

#define TW 8
#define TH 8
#define TILES_W 12
#define TILES_H 12
#define TILE_VOX (96*TW*TH)     // 6144
#define TILE_WORDS (TILE_VOX/32) // 192

#define NBPLANES 11
#define BOUND_VOX (2*NBPLANES*PLANE)       // 202752 = 792*256
#define FACES_PER_VOL (2*2*NBPLANES*PLANE) // 405504 ints
#define MAXR (144*3072)                    // hard max roots/volume
#define EDGE_SLICES (792*4)                // one 32-slot slice per wave
#define EDGE_CAP (EDGE_SLICES*32)          // 101376 u64 per volume

// header: padded counters, one 128-B line each
#define HDR_BYTES 4096
#define H_ACC 0                  // float, line 0
#define H_ROOT(v) (32*(1+(v)))   // int offset, lines 1..8
#define H_EVT(v)  (32*(9+(v)))   // int offset, lines 9..16

// ---------------------------------------------------------------------------
__device__ __forceinline__ int find_root_compress(int* __restrict__ L, int x) {
    int r = x;
    int p = L[r];
    while (p != r) { r = p; p = L[r]; }
    if (r != x) atomicMin(&L[x], r);
    return r;
}

// atomicMin union-find merge; returns # destroyed self-loops (union events).
__device__ __forceinline__ int merge_count(int* __restrict__ L, int l1, int l2) {
    int ev = 0;
    while (l1 != l2) {
        if (l1 < l2) { int t = l1; l1 = l2; l2 = t; }   // l1 > l2
        int l3 = atomicMin(&L[l1], l2);
        if (l3 == l1) { ev++; l1 = l2; }
        else l1 = l3;
    }
    return ev;
}

__device__ __forceinline__ void merge_local(int* lab, int l1, int l2) {
    while (l1 != l2 && l1 != lab[l1]) l1 = lab[l1];
    while (l1 != l2 && l2 != lab[l2]) l2 = lab[l2];
    while (l1 != l2) {
        if (l1 < l2) { int t = l1; l1 = l2; l2 = t; }
        int l3 = atomicMin(&lab[l1], l2);
        l1 = (l3 == l1) ? l2 : l3;
    }
}

__device__ __forceinline__ int run_start(const unsigned* fm, int i, int d) {
    int rowb = (i - d) >> 5;
    int k = d >> 5, bit = d & 31;
    unsigned below = bit ? (~fm[rowb + k] & ((1u << bit) - 1)) : 0u;
    int z = -1;
    if (below) z = (k << 5) + 31 - __builtin_clz(below);
    else if (k > 0) {
        unsigned n1 = ~fm[rowb + k - 1];
        if (n1) z = ((k - 1) << 5) + 31 - __builtin_clz(n1);
        else if (k > 1) {
            unsigned n0 = ~fm[rowb];
            if (n0) z = 31 - __builtin_clz(n0);
        }
    }
    return (i - d) + z + 1;
}

// ---------------------------------------------------------------------------
// Phase 1: run-based per-tile CCL in LDS. Compact rid allocation via ONE
// padded-line atomic per (tile,volume); faces get resolved rids (-1 = bg);
// focal partial fused. No per-voxel label volume.
__global__ __launch_bounds__(256) void ccl_local(const float* __restrict__ pred,
                                                 const float* __restrict__ targ,
                                                 int* __restrict__ faces,
                                                 int* __restrict__ hdr,
                                                 int vbase) {
    __shared__ int lab[TILE_VOX];
    __shared__ unsigned fm[TILE_WORDS];
    __shared__ float fws[4];
    __shared__ int nroots;
    __shared__ int ridbase;

    int vloc = blockIdx.y;
    int v = vbase + vloc;
    int tile = blockIdx.x;
    int tw = tile % TILES_W, th = tile / TILES_W;
    int w0 = tw * TW, h0 = th * TH;
    int tbase = h0 * PLANE + w0 * 96;
    int* Fw  = faces + (size_t)vloc * FACES_PER_VOL;
    int* Fh  = Fw + 2 * NBPLANES * PLANE;
    if (threadIdx.x == 0) nroots = 0;

    float fsum = 0.0f;
    for (int it = 0; it < TILE_VOX / 256; it++) {
        int i = it * 256 + threadIdx.x;
        int lh = i / 768;
        int j = tbase + i + lh * 8448;
        bool f;
        if (v < 4) {
            float xv = pred[(size_t)v * N_VOX + j];
            float tv = targ[(size_t)v * N_VOX + j];
            f = xv > 0.0f;
            float m   = (tv == 1.0f) ? -xv : xv;
            float at  = (tv == 1.0f) ? 0.25f : 0.75f;
            float e   = __expf(-fabsf(m));
            float inv = 1.0f / (1.0f + e);
            float sig = inv * ((m >= 0.0f) ? 1.0f : e);
            float sp  = fmaxf(m, 0.0f) + __logf(1.0f + e);
            fsum += at * sig * sig * sp;
        } else {
            f = targ[(size_t)(v - 4) * N_VOX + j] > 0.5f;
        }
        unsigned long long bal = __ballot(f);
        if ((threadIdx.x & 63) == 0) {
            fm[i >> 5]       = (unsigned)bal;
            fm[(i >> 5) + 1] = (unsigned)(bal >> 32);
        }
        lab[i] = i;
    }
    __syncthreads();

    for (int t = threadIdx.x; t < 336; t += 256) {
        bool wdir = t < 168;
        int tt = wdir ? t : t - 168;
        int lh, lw, k;
        if (wdir) { lh = tt / 21; int rem = tt % 21; lw = rem / 3; k = rem % 3; }
        else      { lh = tt / 24; int rem = tt % 24; lw = rem / 3; k = rem % 3; }
        int wb = (lh * 8 + lw) * 3 + k;
        int nb = wb + (wdir ? 3 : 24);
        unsigned ov = fm[wb] & fm[nb];
        if (!ov) continue;
        unsigned carry = (k > 0) ? ((fm[wb - 1] & fm[nb - 1]) >> 31) : 0u;
        unsigned starts = ov & ~((ov << 1) | carry);
        int base_i = wb << 5;
        int dir = wdir ? 96 : 768;
        while (starts) {
            int b = __builtin_ctz(starts);
            starts &= starts - 1;
            int i = base_i + b;
            int d = (k << 5) + b;
            merge_local(lab, run_start(fm, i, d), run_start(fm, i + dir, d));
        }
    }
    __syncthreads();

    // A1: each ROOT run-start gets a local rank, enc = -2-rank
    for (int t = threadIdx.x; t < TILE_WORDS; t += 256) {
        unsigned m = fm[t];
        if (!m) continue;
        unsigned carry = (t % 3) ? (fm[t - 1] >> 31) : 0u;
        unsigned starts = m & ~((m << 1) | carry);
        int base_i = t << 5;
        while (starts) {
            int b = __builtin_ctz(starts); starts &= starts - 1;
            int i = base_i + b;
            if (lab[i] == i) {
                int rank = atomicAdd(&nroots, 1);
                lab[i] = -2 - rank;
            }
        }
    }
    __syncthreads();

    // A2: non-root run-starts copy their root's enc
    for (int t = threadIdx.x; t < TILE_WORDS; t += 256) {
        unsigned m = fm[t];
        if (!m) continue;
        unsigned carry = (t % 3) ? (fm[t - 1] >> 31) : 0u;
        unsigned starts = m & ~((m << 1) | carry);
        int base_i = t << 5;
        while (starts) {
            int b = __builtin_ctz(starts); starts &= starts - 1;
            int i = base_i + b;
            int p = lab[i];
            if (p >= 0) {
                int r = p; p = lab[r];
                while (p >= 0) { r = p; p = lab[r]; }
                lab[i] = p;
            }
        }
    }
    __syncthreads();

    if (threadIdx.x == 0)
        ridbase = atomicAdd(&hdr[H_ROOT(v)], nroots);   // padded line per volume
    __syncthreads();
    int base = ridbase;

    // faces store (int4 groups)
    for (int t = threadIdx.x; t < 768; t += 256) {
        int f  = t / 192;
        int g  = t % 192;
        int u  = g / 24;
        int d4 = (g % 24) * 4;
        int i0; int* dst;
        if (f == 0) {
            if (tw == 0) continue;
            i0  = u * 768 + d4;
            dst = Fw + ((tw - 1) * 2 + 1) * PLANE + (h0 + u) * 96 + d4;
        } else if (f == 1) {
            if (tw == TILES_W - 1) continue;
            i0  = u * 768 + 7 * 96 + d4;
            dst = Fw + (tw * 2) * PLANE + (h0 + u) * 96 + d4;
        } else if (f == 2) {
            if (th == 0) continue;
            i0  = u * 96 + d4;
            dst = Fh + ((th - 1) * 2 + 1) * PLANE + (w0 + u) * 96 + d4;
        } else {
            if (th == TILES_H - 1) continue;
            i0  = 7 * 768 + u * 96 + d4;
            dst = Fh + (th * 2) * PLANE + (w0 + u) * 96 + d4;
        }
        unsigned mw = fm[i0 >> 5];
        int vals[4];
        bool prevf = false;
        for (int q = 0; q < 4; q++) {
            bool fb = (mw >> ((d4 & 31) + q)) & 1;
            if (fb) vals[q] = prevf ? vals[q - 1]
                                    : base - 2 - lab[run_start(fm, i0 + q, d4 + q)];
            else vals[q] = -1;
            prevf = fb;
        }
        *(int4*)dst = make_int4(vals[0], vals[1], vals[2], vals[3]);
    }

    if (v < 4) {
        for (int off = 32; off; off >>= 1) fsum += __shfl_down(fsum, off, 64);
        int wid = threadIdx.x >> 6;
        if ((threadIdx.x & 63) == 0) fws[wid] = fsum;
        __syncthreads();
        if (threadIdx.x == 0) {
            float ft = fws[0] + fws[1] + fws[2] + fws[3];
            if (ft != 0.0f) atomicAdd((float*)&hdr[H_ACC], ft);
        }
    }
}

// ---------------------------------------------------------------------------
// Phase 2: pure edge extraction with ZERO global atomics. Each wave owns a
// static 32-slot slice (max 32 segment-starts per 64 edges is a hard bound);
// ballot-rank compaction; lane 0 writes the slice count non-atomically.
// Free neighbor-lane dedup via shfl_up.
__global__ __launch_bounds__(256) void ccl_boundary(const int* __restrict__ faces,
                                                    unsigned long long* __restrict__ edges,
                                                    int* __restrict__ counts,
                                                    int vbase) {
    int tid  = blockIdx.x * 256 + threadIdx.x;   // < BOUND_VOX
    int vloc = blockIdx.y;
    const int* F = faces + (size_t)vloc * FACES_PER_VOL;

    int face = tid / PLANE;
    int e    = tid % PLANE;
    const int* A;
    const int* B;
    if (face < NBPLANES) {
        A = F + (face * 2) * PLANE;
        B = F + (face * 2 + 1) * PLANE;
    } else {
        const int* Fh = F + 2 * NBPLANES * PLANE;
        int b = face - NBPLANES;
        A = Fh + (b * 2) * PLANE;
        B = Fh + (b * 2 + 1) * PLANE;
    }

    int a = A[e], b2 = B[e];
    bool want = false;
    unsigned long long key = 0;
    if (a >= 0 && b2 >= 0) {
        int d = e % 96;
        if (d == 0 || A[e - 1] < 0 || B[e - 1] < 0) {   // segment start
            int rmin = a < b2 ? a : b2;
            int rmax = a < b2 ? b2 : a;
            key = ((unsigned long long)rmin << 32) | (unsigned)rmax;
            want = true;
        }
    }

    int lane = threadIdx.x & 63;
    unsigned long long m0 = __ballot(want);
    unsigned long long kup = __shfl_up(key, 1, 64);
    if (want && lane > 0 && ((m0 >> (lane - 1)) & 1) && kup == key) want = false;
    unsigned long long mask = __ballot(want);

    int slice = blockIdx.x * 4 + (threadIdx.x >> 6);
    if (lane == 0) counts[vloc * EDGE_SLICES + slice] = (int)__popcll(mask);
    if (want) {
        int rank = (int)__popcll(mask & ((1ull << lane) - 1));
        edges[(size_t)vloc * EDGE_CAP + slice * 32 + rank] = key;
    }
}

// ---------------------------------------------------------------------------
// Phase 3: one block per volume; union-find on compact rid space (L2-local,
// single XCD). Path-compress then merge; events written non-atomically.
__global__ __launch_bounds__(1024) void ccl_resolve(int* __restrict__ UF,
                                                    const unsigned long long* __restrict__ edges,
                                                    const int* __restrict__ counts,
                                                    int* __restrict__ hdr,
                                                    int vbase) {
    __shared__ int scnt[EDGE_SLICES];
    __shared__ int sred[16];
    int vloc = blockIdx.x;
    int v = vbase + vloc;
    int R = hdr[H_ROOT(v)];
    int* U = UF + (size_t)vloc * MAXR;
    const unsigned long long* E = edges + (size_t)vloc * EDGE_CAP;
    const int* C = counts + vloc * EDGE_SLICES;

    for (int i = threadIdx.x; i < EDGE_SLICES; i += 1024) scnt[i] = C[i];
    for (int i = threadIdx.x; i < R; i += 1024) U[i] = i;
    __syncthreads();

    int ev = 0;
    for (int e = threadIdx.x; e < EDGE_CAP; e += 1024) {
        if ((e & 31) < scnt[e >> 5]) {
            unsigned long long k = E[e];
            int a = find_root_compress(U, (int)(k >> 32));
            int b = find_root_compress(U, (int)(unsigned)k);
            if (a != b) ev += merge_count(U, a, b);
        }
    }
    for (int off = 32; off; off >>= 1) ev += __shfl_down(ev, off, 64);
    if ((threadIdx.x & 63) == 0) sred[threadIdx.x >> 6] = ev;
    __syncthreads();
    if (threadIdx.x == 0) {
        int t = 0;
        for (int w = 0; w < 16; w++) t += sred[w];
        hdr[H_EVT(v)] = t;
    }
}

// ---------------------------------------------------------------------------
__global__ void finalize_kernel(const int* __restrict__ hdr,
                                float* __restrict__ out) {
    float focal = ((const float*)hdr)[H_ACC] / (float)NEL;
    float c[NVOL];
    for (int v = 0; v < NVOL; v++)
        c[v] = (float)(hdr[H_ROOT(v)] - hdr[H_EVT(v)]);
    float dp0 = 0.5f * (c[0] + c[2]);
    float dp1 = 0.5f * (c[1] + c[3]);
    float dt0 = 0.5f * (c[4] + c[6]);
    float dt1 = 0.5f * (c[5] + c[7]);
    float topo = 0.5f * (fabsf(dp0 - dt0) + fabsf(dp1 - dt1));
    out[0] = focal + 0.1f * topo;
}

// ---------------------------------------------------------------------------
extern "C" void kernel_launch(void* const* d_in, const int* in_sizes, int n_in,
                              void* d_out, int out_size, void* d_ws, size_t ws_size,
                              hipStream_t stream) {
    const float* pred = (const float*)d_in[0];
    const float* targ = (const float*)d_in[1];
    float* out = (float*)d_out;

    int* hdr = (int*)d_ws;
    char* body = (char*)d_ws + HDR_BYTES;

    // body layout (edges first for 8B alignment):
    // edges[vp*EDGE_CAP] u64 | UF[vp*MAXR] | faces[vp*FACES_PER_VOL] | counts[vp*EDGE_SLICES]
    size_t per_vol = 2 * (size_t)EDGE_CAP + MAXR + FACES_PER_VOL + EDGE_SLICES; // ints
    size_t avail_ints = (ws_size > HDR_BYTES) ? (ws_size - HDR_BYTES) / 4 : 0;
    int vols_per_pass = (int)(avail_ints / per_vol);
    if (vols_per_pass > NVOL) vols_per_pass = NVOL;
    if (vols_per_pass < 1) vols_per_pass = 1;

    unsigned long long* edges = (unsigned long long*)body;
    int* UF     = (int*)(edges + (size_t)vols_per_pass * EDGE_CAP);
    int* faces  = UF + (size_t)vols_per_pass * MAXR;
    int* counts = faces + (size_t)vols_per_pass * FACES_PER_VOL;

    hipMemsetAsync(d_ws, 0, HDR_BYTES, stream);

    for (int vbase = 0; vbase < NVOL; vbase += vols_per_pass) {
        int nv = NVOL - vbase;
        if (nv > vols_per_pass) nv = vols_per_pass;
        dim3 tgrid(TILES_W * TILES_H, nv);
        ccl_local<<<tgrid, dim3(256), 0, stream>>>(pred, targ, faces, hdr, vbase);
        dim3 bgrid(BOUND_VOX / 256, nv);
        ccl_boundary<<<bgrid, dim3(256), 0, stream>>>(faces, edges, counts, vbase);
        ccl_resolve<<<dim3(nv), dim3(1024), 0, stream>>>(UF, edges, counts, hdr, vbase);
    }

    finalize_kernel<<<1, 1, 0, stream>>>(hdr, out);
}

// Round 11
// 245.522 us; speedup vs baseline: 2.7380x; 2.7380x over previous
//
#include <hip/hip_runtime.h>
#include <math.h>
#include <limits.h>

#define N_VOX (96*96*96)        // 884736 voxels per volume
#define NVOL 8                  // 4 pred + 4 target volumes
#define NEL (4*N_VOX)           // 3538944 elements in pred/target
#define PLANE (96*96)           // 9216

#define TW 8
#define TH 8
#define TILES_W 12
#define TILES_H 12
#define TILE_VOX (96*TW*TH)     // 6144
#define TILE_WORDS (TILE_VOX/32) // 192

#define NBPLANES 11
#define BOUND_VOX (2*NBPLANES*PLANE)       // 202752 = 792*256
#define FACES_PER_VOL (2*2*NBPLANES*PLANE) // 405504 ints
#define MAXR (144*1536)                    // worst-case boundary roots/volume
#define EDGE_SLICES (792*4)                // one 32-slot slice per wave
#define EDGE_CAP (EDGE_SLICES*32)          // 101376 u64 per volume
#define UF_LDS 15360                       // LDS union-find capacity (60 KB)

// header: padded counters, one 128-B line each (int offsets)
#define HDR_BYTES 4096
#define H_ACC 0                  // float, line 0
#define H_ROOT(v) (32*(1+(v)))   // total roots, lines 1..8
#define H_EVT(v)  (32*(9+(v)))   // union events, lines 9..16
#define H_RIDB(v) (32*(17+(v)))  // boundary-rid allocator, lines 17..24

// ---------------------------------------------------------------------------
__device__ __forceinline__ int find_root_compress(int* __restrict__ L, int x) {
    int r = x;
    int p = L[r];
    while (p != r) { r = p; p = L[r]; }
    if (r != x) atomicMin(&L[x], r);
    return r;
}

// atomicMin union-find merge; returns # destroyed self-loops (union events).
__device__ __forceinline__ int merge_count(int* __restrict__ L, int l1, int l2) {
    int ev = 0;
    while (l1 != l2) {
        if (l1 < l2) { int t = l1; l1 = l2; l2 = t; }   // l1 > l2
        int l3 = atomicMin(&L[l1], l2);
        if (l3 == l1) { ev++; l1 = l2; }
        else l1 = l3;
    }
    return ev;
}

__device__ __forceinline__ void merge_local(int* lab, int l1, int l2) {
    while (l1 != l2 && l1 != lab[l1]) l1 = lab[l1];
    while (l1 != l2 && l2 != lab[l2]) l2 = lab[l2];
    while (l1 != l2) {
        if (l1 < l2) { int t = l1; l1 = l2; l2 = t; }
        int l3 = atomicMin(&lab[l1], l2);
        l1 = (l3 == l1) ? l2 : l3;
    }
}

__device__ __forceinline__ int run_start(const unsigned* fm, int i, int d) {
    int rowb = (i - d) >> 5;
    int k = d >> 5, bit = d & 31;
    unsigned below = bit ? (~fm[rowb + k] & ((1u << bit) - 1)) : 0u;
    int z = -1;
    if (below) z = (k << 5) + 31 - __builtin_clz(below);
    else if (k > 0) {
        unsigned n1 = ~fm[rowb + k - 1];
        if (n1) z = ((k - 1) << 5) + 31 - __builtin_clz(n1);
        else if (k > 1) {
            unsigned n0 = ~fm[rowb];
            if (n0) z = 31 - __builtin_clz(n0);
        }
    }
    return (i - d) + z + 1;
}

// ---------------------------------------------------------------------------
// Phase 1: run-based per-tile CCL in LDS. Face-touching roots get compact
// boundary ids (UF space); interior roots are only counted. Faces store
// resolved boundary rids (-1 = bg). Focal partial fused.
__global__ __launch_bounds__(256) void ccl_local(const float* __restrict__ pred,
                                                 const float* __restrict__ targ,
                                                 int* __restrict__ faces,
                                                 int* __restrict__ hdr,
                                                 int vbase) {
    __shared__ int lab[TILE_VOX];
    __shared__ unsigned fm[TILE_WORDS];
    __shared__ unsigned mark[TILE_WORDS];    // face-touching root bitmap
    __shared__ float fws[4];
    __shared__ int nb, ni;                   // boundary / interior root counts
    __shared__ int ridbase;

    int vloc = blockIdx.y;
    int v = vbase + vloc;
    int tile = blockIdx.x;
    int tw = tile % TILES_W, th = tile / TILES_W;
    int w0 = tw * TW, h0 = th * TH;
    int tbase = h0 * PLANE + w0 * 96;
    int* Fw  = faces + (size_t)vloc * FACES_PER_VOL;
    int* Fh  = Fw + 2 * NBPLANES * PLANE;
    if (threadIdx.x == 0) { nb = 0; ni = 0; }
    for (int t = threadIdx.x; t < TILE_WORDS; t += 256) mark[t] = 0u;

    float fsum = 0.0f;
    for (int it = 0; it < TILE_VOX / 256; it++) {
        int i = it * 256 + threadIdx.x;
        int lh = i / 768;
        int j = tbase + i + lh * 8448;
        bool f;
        if (v < 4) {
            float xv = pred[(size_t)v * N_VOX + j];
            float tv = targ[(size_t)v * N_VOX + j];
            f = xv > 0.0f;
            float m   = (tv == 1.0f) ? -xv : xv;
            float at  = (tv == 1.0f) ? 0.25f : 0.75f;
            float e   = __expf(-fabsf(m));
            float inv = 1.0f / (1.0f + e);
            float sig = inv * ((m >= 0.0f) ? 1.0f : e);
            float sp  = fmaxf(m, 0.0f) + __logf(1.0f + e);
            fsum += at * sig * sig * sp;
        } else {
            f = targ[(size_t)(v - 4) * N_VOX + j] > 0.5f;
        }
        unsigned long long bal = __ballot(f);
        if ((threadIdx.x & 63) == 0) {
            fm[i >> 5]       = (unsigned)bal;
            fm[(i >> 5) + 1] = (unsigned)(bal >> 32);
        }
        lab[i] = i;
    }
    __syncthreads();

    // intra-tile merges at overlap-segment starts
    for (int t = threadIdx.x; t < 336; t += 256) {
        bool wdir = t < 168;
        int tt = wdir ? t : t - 168;
        int lh, lw, k;
        if (wdir) { lh = tt / 21; int rem = tt % 21; lw = rem / 3; k = rem % 3; }
        else      { lh = tt / 24; int rem = tt % 24; lw = rem / 3; k = rem % 3; }
        int wb = (lh * 8 + lw) * 3 + k;
        int nbw = wb + (wdir ? 3 : 24);
        unsigned ov = fm[wb] & fm[nbw];
        if (!ov) continue;
        unsigned carry = (k > 0) ? ((fm[wb - 1] & fm[nbw - 1]) >> 31) : 0u;
        unsigned starts = ov & ~((ov << 1) | carry);
        int base_i = wb << 5;
        int dir = wdir ? 96 : 768;
        while (starts) {
            int b = __builtin_ctz(starts);
            starts &= starts - 1;
            int i = base_i + b;
            int d = (k << 5) + b;
            merge_local(lab, run_start(fm, i, d), run_start(fm, i + dir, d));
        }
    }
    __syncthreads();

    // M: mark roots of run-starts on the 4 stored faces (rows with lw in
    // {0,7} or lh in {0,7}); 32 rows x 3 words = 96 tasks.
    for (int t = threadIdx.x; t < 96; t += 256) {
        int rowsel = t / 3, k = t % 3;
        int lh, lw;
        if (rowsel < 8)       { lh = rowsel;      lw = 0; }
        else if (rowsel < 16) { lh = rowsel - 8;  lw = 7; }
        else if (rowsel < 24) { lh = 0;           lw = rowsel - 16; }
        else                  { lh = 7;           lw = rowsel - 24; }
        int wb = (lh * 8 + lw) * 3 + k;
        unsigned m = fm[wb];
        if (!m) continue;
        unsigned carry = k ? (fm[wb - 1] >> 31) : 0u;
        unsigned starts = m & ~((m << 1) | carry);
        int base_i = wb << 5;
        while (starts) {
            int b = __builtin_ctz(starts); starts &= starts - 1;
            int r = base_i + b;
            while (lab[r] != r) r = lab[r];
            atomicOr(&mark[r >> 5], 1u << (r & 31));
        }
    }
    __syncthreads();

    // A1: marked roots get boundary rank enc=-2-rank; interior roots counted,
    // enc = INT_MIN (never read by face stores).
    for (int t = threadIdx.x; t < TILE_WORDS; t += 256) {
        unsigned m = fm[t];
        if (!m) continue;
        unsigned carry = (t % 3) ? (fm[t - 1] >> 31) : 0u;
        unsigned starts = m & ~((m << 1) | carry);
        int base_i = t << 5;
        while (starts) {
            int b = __builtin_ctz(starts); starts &= starts - 1;
            int i = base_i + b;
            if (lab[i] == i) {
                if ((mark[i >> 5] >> (i & 31)) & 1) {
                    int rank = atomicAdd(&nb, 1);
                    lab[i] = -2 - rank;
                } else {
                    atomicAdd(&ni, 1);
                    lab[i] = INT_MIN;
                }
            }
        }
    }
    __syncthreads();

    // A2: non-root run-starts copy their root's enc (walk ends at <0)
    for (int t = threadIdx.x; t < TILE_WORDS; t += 256) {
        unsigned m = fm[t];
        if (!m) continue;
        unsigned carry = (t % 3) ? (fm[t - 1] >> 31) : 0u;
        unsigned starts = m & ~((m << 1) | carry);
        int base_i = t << 5;
        while (starts) {
            int b = __builtin_ctz(starts); starts &= starts - 1;
            int i = base_i + b;
            int p = lab[i];
            if (p >= 0) {
                int r = p; p = lab[r];
                while (p >= 0) { r = p; p = lab[r]; }
                lab[i] = p;
            }
        }
    }
    __syncthreads();

    if (threadIdx.x == 0) {
        ridbase = atomicAdd(&hdr[H_RIDB(v)], nb);
        atomicAdd(&hdr[H_ROOT(v)], nb + ni);
    }
    __syncthreads();
    int base = ridbase;

    // faces store (int4 groups); every enc read here is a boundary enc
    for (int t = threadIdx.x; t < 768; t += 256) {
        int f  = t / 192;
        int g  = t % 192;
        int u  = g / 24;
        int d4 = (g % 24) * 4;
        int i0; int* dst;
        if (f == 0) {
            if (tw == 0) continue;
            i0  = u * 768 + d4;
            dst = Fw + ((tw - 1) * 2 + 1) * PLANE + (h0 + u) * 96 + d4;
        } else if (f == 1) {
            if (tw == TILES_W - 1) continue;
            i0  = u * 768 + 7 * 96 + d4;
            dst = Fw + (tw * 2) * PLANE + (h0 + u) * 96 + d4;
        } else if (f == 2) {
            if (th == 0) continue;
            i0  = u * 96 + d4;
            dst = Fh + ((th - 1) * 2 + 1) * PLANE + (w0 + u) * 96 + d4;
        } else {
            if (th == TILES_H - 1) continue;
            i0  = 7 * 768 + u * 96 + d4;
            dst = Fh + (th * 2) * PLANE + (w0 + u) * 96 + d4;
        }
        unsigned mw = fm[i0 >> 5];
        int vals[4];
        bool prevf = false;
        for (int q = 0; q < 4; q++) {
            bool fb = (mw >> ((d4 & 31) + q)) & 1;
            if (fb) vals[q] = prevf ? vals[q - 1]
                                    : base - 2 - lab[run_start(fm, i0 + q, d4 + q)];
            else vals[q] = -1;
            prevf = fb;
        }
        *(int4*)dst = make_int4(vals[0], vals[1], vals[2], vals[3]);
    }

    if (v < 4) {
        for (int off = 32; off; off >>= 1) fsum += __shfl_down(fsum, off, 64);
        int wid = threadIdx.x >> 6;
        if ((threadIdx.x & 63) == 0) fws[wid] = fsum;
        __syncthreads();
        if (threadIdx.x == 0) {
            float ft = fws[0] + fws[1] + fws[2] + fws[3];
            if (ft != 0.0f) atomicAdd((float*)&hdr[H_ACC], ft);
        }
    }
}

// ---------------------------------------------------------------------------
// Phase 2: pure edge extraction, ZERO global atomics. Each wave owns a static
// 32-slot slice; ballot-rank compaction; lane 0 writes the slice count.
__global__ __launch_bounds__(256) void ccl_boundary(const int* __restrict__ faces,
                                                    unsigned long long* __restrict__ edges,
                                                    int* __restrict__ counts,
                                                    int vbase) {
    int tid  = blockIdx.x * 256 + threadIdx.x;   // < BOUND_VOX
    int vloc = blockIdx.y;
    const int* F = faces + (size_t)vloc * FACES_PER_VOL;

    int face = tid / PLANE;
    int e    = tid % PLANE;
    const int* A;
    const int* B;
    if (face < NBPLANES) {
        A = F + (face * 2) * PLANE;
        B = F + (face * 2 + 1) * PLANE;
    } else {
        const int* Fh = F + 2 * NBPLANES * PLANE;
        int b = face - NBPLANES;
        A = Fh + (b * 2) * PLANE;
        B = Fh + (b * 2 + 1) * PLANE;
    }

    int a = A[e], b2 = B[e];
    bool want = false;
    unsigned long long key = 0;
    if (a >= 0 && b2 >= 0) {
        int d = e % 96;
        if (d == 0 || A[e - 1] < 0 || B[e - 1] < 0) {   // segment start
            int rmin = a < b2 ? a : b2;
            int rmax = a < b2 ? b2 : a;
            key = ((unsigned long long)rmin << 32) | (unsigned)rmax;
            want = true;
        }
    }

    int lane = threadIdx.x & 63;
    unsigned long long m0 = __ballot(want);
    unsigned long long kup = __shfl_up(key, 1, 64);
    if (want && lane > 0 && ((m0 >> (lane - 1)) & 1) && kup == key) want = false;
    unsigned long long mask = __ballot(want);

    int slice = blockIdx.x * 4 + (threadIdx.x >> 6);
    if (lane == 0) counts[vloc * EDGE_SLICES + slice] = (int)__popcll(mask);
    if (want) {
        int rank = (int)__popcll(mask & ((1ull << lane) - 1));
        edges[(size_t)vloc * EDGE_CAP + slice * 32 + rank] = key;
    }
}

// ---------------------------------------------------------------------------
// Phase 3: one block per volume; union-find in LDS (R <= UF_LDS, the normal
// case) -> all finds/merges are LDS atomics, no global contention. Global
// fallback kept for the adversarial R > UF_LDS case.
__global__ __launch_bounds__(1024) void ccl_resolve(int* __restrict__ UFg,
                                                    const unsigned long long* __restrict__ edges,
                                                    const int* __restrict__ counts,
                                                    int* __restrict__ hdr,
                                                    int vbase) {
    __shared__ int U[UF_LDS];                // 60 KB
    __shared__ int sred[16];
    int vloc = blockIdx.x;
    int v = vbase + vloc;
    int R = hdr[H_RIDB(v)];
    const unsigned long long* E = edges + (size_t)vloc * EDGE_CAP;
    const int* C = counts + vloc * EDGE_SLICES;

    int ev = 0;
    if (R <= UF_LDS) {
        for (int i = threadIdx.x; i < R; i += 1024) U[i] = i;
        __syncthreads();
        for (int e = threadIdx.x; e < EDGE_CAP; e += 1024) {
            if ((e & 31) < C[e >> 5]) {
                unsigned long long k = E[e];
                int a = find_root_compress(U, (int)(k >> 32));
                int b = find_root_compress(U, (int)(unsigned)k);
                if (a != b) ev += merge_count(U, a, b);
            }
        }
    } else {
        int* Ug = UFg + (size_t)vloc * MAXR;
        for (int i = threadIdx.x; i < R; i += 1024) Ug[i] = i;
        __syncthreads();
        for (int e = threadIdx.x; e < EDGE_CAP; e += 1024) {
            if ((e & 31) < C[e >> 5]) {
                unsigned long long k = E[e];
                int a = find_root_compress(Ug, (int)(k >> 32));
                int b = find_root_compress(Ug, (int)(unsigned)k);
                if (a != b) ev += merge_count(Ug, a, b);
            }
        }
    }
    for (int off = 32; off; off >>= 1) ev += __shfl_down(ev, off, 64);
    if ((threadIdx.x & 63) == 0) sred[threadIdx.x >> 6] = ev;
    __syncthreads();
    if (threadIdx.x == 0) {
        int t = 0;
        for (int w = 0; w < 16; w++) t += sred[w];
        hdr[H_EVT(v)] = t;
    }
}

// ---------------------------------------------------------------------------
__global__ void finalize_kernel(const int* __restrict__ hdr,
                                float* __restrict__ out) {
    float focal = ((const float*)hdr)[H_ACC] / (float)NEL;
    float c[NVOL];
    for (int v = 0; v < NVOL; v++)
        c[v] = (float)(hdr[H_ROOT(v)] - hdr[H_EVT(v)]);
    float dp0 = 0.5f * (c[0] + c[2]);
    float dp1 = 0.5f * (c[1] + c[3]);
    float dt0 = 0.5f * (c[4] + c[6]);
    float dt1 = 0.5f * (c[5] + c[7]);
    float topo = 0.5f * (fabsf(dp0 - dt0) + fabsf(dp1 - dt1));
    out[0] = focal + 0.1f * topo;
}

// ---------------------------------------------------------------------------
extern "C" void kernel_launch(void* const* d_in, const int* in_sizes, int n_in,
                              void* d_out, int out_size, void* d_ws, size_t ws_size,
                              hipStream_t stream) {
    const float* pred = (const float*)d_in[0];
    const float* targ = (const float*)d_in[1];
    float* out = (float*)d_out;

    int* hdr = (int*)d_ws;
    char* body = (char*)d_ws + HDR_BYTES;

    // body: edges[vp*EDGE_CAP] u64 | UF[vp*MAXR] | faces[vp*FACES_PER_VOL] |
    //       counts[vp*EDGE_SLICES]
    size_t per_vol = 2 * (size_t)EDGE_CAP + MAXR + FACES_PER_VOL + EDGE_SLICES;
    size_t avail_ints = (ws_size > HDR_BYTES) ? (ws_size - HDR_BYTES) / 4 : 0;
    int vols_per_pass = (int)(avail_ints / per_vol);
    if (vols_per_pass > NVOL) vols_per_pass = NVOL;
    if (vols_per_pass < 1) vols_per_pass = 1;

    unsigned long long* edges = (unsigned long long*)body;
    int* UF     = (int*)(edges + (size_t)vols_per_pass * EDGE_CAP);
    int* faces  = UF + (size_t)vols_per_pass * MAXR;
    int* counts = faces + (size_t)vols_per_pass * FACES_PER_VOL;

    hipMemsetAsync(d_ws, 0, HDR_BYTES, stream);

    for (int vbase = 0; vbase < NVOL; vbase += vols_per_pass) {
        int nv = NVOL - vbase;
        if (nv > vols_per_pass) nv = vols_per_pass;
        dim3 tgrid(TILES_W * TILES_H, nv);
        ccl_local<<<tgrid, dim3(256), 0, stream>>>(pred, targ, faces, hdr, vbase);
        dim3 bgrid(BOUND_VOX / 256, nv);
        ccl_boundary<<<bgrid, dim3(256), 0, stream>>>(faces, edges, counts, vbase);
        ccl_resolve<<<dim3(nv), dim3(1024), 0, stream>>>(UF, edges, counts, hdr, vbase);
    }

    finalize_kernel<<<1, 1, 0, stream>>>(hdr, out);
}

// Round 12
// 239.046 us; speedup vs baseline: 2.8122x; 1.0271x over previous
//
#include <hip/hip_runtime.h>
#include <math.h>
#include <limits.h>

#define N_VOX (96*96*96)        // 884736 voxels per volume
#define NVOL 8                  // 4 pred + 4 target volumes
#define NEL (4*N_VOX)           // 3538944 elements in pred/target
#define PLANE (96*96)           // 9216

#define TW 8
#define TH 8
#define TILES_W 12
#define TILES_H 12
#define TILE_VOX (96*TW*TH)     // 6144
#define TILE_WORDS (TILE_VOX/32) // 192

#define NBPLANES 11
#define BOUND_VOX (2*NBPLANES*PLANE)       // 202752 = 792*256
#define FACES_PER_VOL (2*2*NBPLANES*PLANE) // 405504 ints
#define MAXR (144*1536)                    // worst-case boundary roots/volume
#define EDGE_SLICES (792*4)                // one 32-slot slice per wave
#define EDGE_CAP (EDGE_SLICES*32)          // 101376 u64 per volume
#define UF_LDS 15360                       // LDS union-find capacity (60 KB)

// header: padded counters, one 128-B line each (int offsets)
#define HDR_BYTES 4096
#define H_ACC 0                  // float, line 0
#define H_ROOT(v) (32*(1+(v)))   // total roots, lines 1..8
#define H_EVT(v)  (32*(9+(v)))   // union events, lines 9..16
#define H_RIDB(v) (32*(17+(v)))  // boundary-rid allocator, lines 17..24

// ---------------------------------------------------------------------------
// READ-ONLY find: no compression writes. In the rid space every node starts
// as a root, so tree depth grows only via merges (stays ~log E); the
// unconditional atomicMin write-back in the old find was the LDS-atomic
// storm (476k bank conflicts), not a win.
__device__ __forceinline__ int find_ro(const int* __restrict__ L, int x) {
    int r = x;
    int p = L[r];
    while (p != r) { r = p; p = L[r]; }
    return r;
}

// atomicMin union-find merge; returns # destroyed self-loops (union events).
__device__ __forceinline__ int merge_count(int* __restrict__ L, int l1, int l2) {
    int ev = 0;
    while (l1 != l2) {
        if (l1 < l2) { int t = l1; l1 = l2; l2 = t; }   // l1 > l2
        int l3 = atomicMin(&L[l1], l2);
        if (l3 == l1) { ev++; l1 = l2; }
        else l1 = l3;
    }
    return ev;
}

__device__ __forceinline__ void merge_local(int* lab, int l1, int l2) {
    while (l1 != l2 && l1 != lab[l1]) l1 = lab[l1];
    while (l1 != l2 && l2 != lab[l2]) l2 = lab[l2];
    while (l1 != l2) {
        if (l1 < l2) { int t = l1; l1 = l2; l2 = t; }
        int l3 = atomicMin(&lab[l1], l2);
        l1 = (l3 == l1) ? l2 : l3;
    }
}

__device__ __forceinline__ int run_start(const unsigned* fm, int i, int d) {
    int rowb = (i - d) >> 5;
    int k = d >> 5, bit = d & 31;
    unsigned below = bit ? (~fm[rowb + k] & ((1u << bit) - 1)) : 0u;
    int z = -1;
    if (below) z = (k << 5) + 31 - __builtin_clz(below);
    else if (k > 0) {
        unsigned n1 = ~fm[rowb + k - 1];
        if (n1) z = ((k - 1) << 5) + 31 - __builtin_clz(n1);
        else if (k > 1) {
            unsigned n0 = ~fm[rowb];
            if (n0) z = 31 - __builtin_clz(n0);
        }
    }
    return (i - d) + z + 1;
}

// ---------------------------------------------------------------------------
// Phase 1: run-based per-tile CCL in LDS. Face-touching roots get compact
// boundary ids (UF space); interior roots are only counted. Faces store
// resolved boundary rids (-1 = bg). Focal partial fused.
__global__ __launch_bounds__(256) void ccl_local(const float* __restrict__ pred,
                                                 const float* __restrict__ targ,
                                                 int* __restrict__ faces,
                                                 int* __restrict__ hdr,
                                                 int vbase) {
    __shared__ int lab[TILE_VOX];
    __shared__ unsigned fm[TILE_WORDS];
    __shared__ unsigned mark[TILE_WORDS];    // face-touching root bitmap
    __shared__ float fws[4];
    __shared__ int nb, ni;                   // boundary / interior root counts
    __shared__ int ridbase;

    int vloc = blockIdx.y;
    int v = vbase + vloc;
    int tile = blockIdx.x;
    int tw = tile % TILES_W, th = tile / TILES_W;
    int w0 = tw * TW, h0 = th * TH;
    int tbase = h0 * PLANE + w0 * 96;
    int* Fw  = faces + (size_t)vloc * FACES_PER_VOL;
    int* Fh  = Fw + 2 * NBPLANES * PLANE;
    if (threadIdx.x == 0) { nb = 0; ni = 0; }
    for (int t = threadIdx.x; t < TILE_WORDS; t += 256) mark[t] = 0u;

    float fsum = 0.0f;
    for (int it = 0; it < TILE_VOX / 256; it++) {
        int i = it * 256 + threadIdx.x;
        int lh = i / 768;
        int j = tbase + i + lh * 8448;
        bool f;
        if (v < 4) {
            float xv = pred[(size_t)v * N_VOX + j];
            float tv = targ[(size_t)v * N_VOX + j];
            f = xv > 0.0f;
            float m   = (tv == 1.0f) ? -xv : xv;
            float at  = (tv == 1.0f) ? 0.25f : 0.75f;
            float e   = __expf(-fabsf(m));
            float inv = 1.0f / (1.0f + e);
            float sig = inv * ((m >= 0.0f) ? 1.0f : e);
            float sp  = fmaxf(m, 0.0f) + __logf(1.0f + e);
            fsum += at * sig * sig * sp;
        } else {
            f = targ[(size_t)(v - 4) * N_VOX + j] > 0.5f;
        }
        unsigned long long bal = __ballot(f);
        if ((threadIdx.x & 63) == 0) {
            fm[i >> 5]       = (unsigned)bal;
            fm[(i >> 5) + 1] = (unsigned)(bal >> 32);
        }
        lab[i] = i;
    }
    __syncthreads();

    // intra-tile merges at overlap-segment starts
    for (int t = threadIdx.x; t < 336; t += 256) {
        bool wdir = t < 168;
        int tt = wdir ? t : t - 168;
        int lh, lw, k;
        if (wdir) { lh = tt / 21; int rem = tt % 21; lw = rem / 3; k = rem % 3; }
        else      { lh = tt / 24; int rem = tt % 24; lw = rem / 3; k = rem % 3; }
        int wb = (lh * 8 + lw) * 3 + k;
        int nbw = wb + (wdir ? 3 : 24);
        unsigned ov = fm[wb] & fm[nbw];
        if (!ov) continue;
        unsigned carry = (k > 0) ? ((fm[wb - 1] & fm[nbw - 1]) >> 31) : 0u;
        unsigned starts = ov & ~((ov << 1) | carry);
        int base_i = wb << 5;
        int dir = wdir ? 96 : 768;
        while (starts) {
            int b = __builtin_ctz(starts);
            starts &= starts - 1;
            int i = base_i + b;
            int d = (k << 5) + b;
            merge_local(lab, run_start(fm, i, d), run_start(fm, i + dir, d));
        }
    }
    __syncthreads();

    // M: mark roots of run-starts on the 4 stored faces
    for (int t = threadIdx.x; t < 96; t += 256) {
        int rowsel = t / 3, k = t % 3;
        int lh, lw;
        if (rowsel < 8)       { lh = rowsel;      lw = 0; }
        else if (rowsel < 16) { lh = rowsel - 8;  lw = 7; }
        else if (rowsel < 24) { lh = 0;           lw = rowsel - 16; }
        else                  { lh = 7;           lw = rowsel - 24; }
        int wb = (lh * 8 + lw) * 3 + k;
        unsigned m = fm[wb];
        if (!m) continue;
        unsigned carry = k ? (fm[wb - 1] >> 31) : 0u;
        unsigned starts = m & ~((m << 1) | carry);
        int base_i = wb << 5;
        while (starts) {
            int b = __builtin_ctz(starts); starts &= starts - 1;
            int r = base_i + b;
            while (lab[r] != r) r = lab[r];
            atomicOr(&mark[r >> 5], 1u << (r & 31));
        }
    }
    __syncthreads();

    // A1: marked roots get boundary rank enc=-2-rank; interior roots counted
    for (int t = threadIdx.x; t < TILE_WORDS; t += 256) {
        unsigned m = fm[t];
        if (!m) continue;
        unsigned carry = (t % 3) ? (fm[t - 1] >> 31) : 0u;
        unsigned starts = m & ~((m << 1) | carry);
        int base_i = t << 5;
        while (starts) {
            int b = __builtin_ctz(starts); starts &= starts - 1;
            int i = base_i + b;
            if (lab[i] == i) {
                if ((mark[i >> 5] >> (i & 31)) & 1) {
                    int rank = atomicAdd(&nb, 1);
                    lab[i] = -2 - rank;
                } else {
                    atomicAdd(&ni, 1);
                    lab[i] = INT_MIN;
                }
            }
        }
    }
    __syncthreads();

    // A2: non-root run-starts copy their root's enc (walk ends at <0)
    for (int t = threadIdx.x; t < TILE_WORDS; t += 256) {
        unsigned m = fm[t];
        if (!m) continue;
        unsigned carry = (t % 3) ? (fm[t - 1] >> 31) : 0u;
        unsigned starts = m & ~((m << 1) | carry);
        int base_i = t << 5;
        while (starts) {
            int b = __builtin_ctz(starts); starts &= starts - 1;
            int i = base_i + b;
            int p = lab[i];
            if (p >= 0) {
                int r = p; p = lab[r];
                while (p >= 0) { r = p; p = lab[r]; }
                lab[i] = p;
            }
        }
    }
    __syncthreads();

    if (threadIdx.x == 0) {
        ridbase = atomicAdd(&hdr[H_RIDB(v)], nb);
        atomicAdd(&hdr[H_ROOT(v)], nb + ni);
    }
    __syncthreads();
    int base = ridbase;

    // faces store (int4 groups); every enc read here is a boundary enc
    for (int t = threadIdx.x; t < 768; t += 256) {
        int f  = t / 192;
        int g  = t % 192;
        int u  = g / 24;
        int d4 = (g % 24) * 4;
        int i0; int* dst;
        if (f == 0) {
            if (tw == 0) continue;
            i0  = u * 768 + d4;
            dst = Fw + ((tw - 1) * 2 + 1) * PLANE + (h0 + u) * 96 + d4;
        } else if (f == 1) {
            if (tw == TILES_W - 1) continue;
            i0  = u * 768 + 7 * 96 + d4;
            dst = Fw + (tw * 2) * PLANE + (h0 + u) * 96 + d4;
        } else if (f == 2) {
            if (th == 0) continue;
            i0  = u * 96 + d4;
            dst = Fh + ((th - 1) * 2 + 1) * PLANE + (w0 + u) * 96 + d4;
        } else {
            if (th == TILES_H - 1) continue;
            i0  = 7 * 768 + u * 96 + d4;
            dst = Fh + (th * 2) * PLANE + (w0 + u) * 96 + d4;
        }
        unsigned mw = fm[i0 >> 5];
        int vals[4];
        bool prevf = false;
        for (int q = 0; q < 4; q++) {
            bool fb = (mw >> ((d4 & 31) + q)) & 1;
            if (fb) vals[q] = prevf ? vals[q - 1]
                                    : base - 2 - lab[run_start(fm, i0 + q, d4 + q)];
            else vals[q] = -1;
            prevf = fb;
        }
        *(int4*)dst = make_int4(vals[0], vals[1], vals[2], vals[3]);
    }

    if (v < 4) {
        for (int off = 32; off; off >>= 1) fsum += __shfl_down(fsum, off, 64);
        int wid = threadIdx.x >> 6;
        if ((threadIdx.x & 63) == 0) fws[wid] = fsum;
        __syncthreads();
        if (threadIdx.x == 0) {
            float ft = fws[0] + fws[1] + fws[2] + fws[3];
            if (ft != 0.0f) atomicAdd((float*)&hdr[H_ACC], ft);
        }
    }
}

// ---------------------------------------------------------------------------
// Phase 2: pure edge extraction, ZERO global atomics.
__global__ __launch_bounds__(256) void ccl_boundary(const int* __restrict__ faces,
                                                    unsigned long long* __restrict__ edges,
                                                    int* __restrict__ counts,
                                                    int vbase) {
    int tid  = blockIdx.x * 256 + threadIdx.x;   // < BOUND_VOX
    int vloc = blockIdx.y;
    const int* F = faces + (size_t)vloc * FACES_PER_VOL;

    int face = tid / PLANE;
    int e    = tid % PLANE;
    const int* A;
    const int* B;
    if (face < NBPLANES) {
        A = F + (face * 2) * PLANE;
        B = F + (face * 2 + 1) * PLANE;
    } else {
        const int* Fh = F + 2 * NBPLANES * PLANE;
        int b = face - NBPLANES;
        A = Fh + (b * 2) * PLANE;
        B = Fh + (b * 2 + 1) * PLANE;
    }

    int a = A[e], b2 = B[e];
    bool want = false;
    unsigned long long key = 0;
    if (a >= 0 && b2 >= 0) {
        int d = e % 96;
        if (d == 0 || A[e - 1] < 0 || B[e - 1] < 0) {   // segment start
            int rmin = a < b2 ? a : b2;
            int rmax = a < b2 ? b2 : a;
            key = ((unsigned long long)rmin << 32) | (unsigned)rmax;
            want = true;
        }
    }

    int lane = threadIdx.x & 63;
    unsigned long long m0 = __ballot(want);
    unsigned long long kup = __shfl_up(key, 1, 64);
    if (want && lane > 0 && ((m0 >> (lane - 1)) & 1) && kup == key) want = false;
    unsigned long long mask = __ballot(want);

    int slice = blockIdx.x * 4 + (threadIdx.x >> 6);
    if (lane == 0) counts[vloc * EDGE_SLICES + slice] = (int)__popcll(mask);
    if (want) {
        int rank = (int)__popcll(mask & ((1ull << lane) - 1));
        edges[(size_t)vloc * EDGE_CAP + slice * 32 + rank] = key;
    }
}

// ---------------------------------------------------------------------------
// Phase 3: one block per volume; union-find in LDS. Finds are READ-ONLY
// (broadcast-friendly, zero atomics); merge only when roots differ. No
// path-compression writes: rid-space trees start flat and deepen only ~log E.
__global__ __launch_bounds__(1024) void ccl_resolve(int* __restrict__ UFg,
                                                    const unsigned long long* __restrict__ edges,
                                                    const int* __restrict__ counts,
                                                    int* __restrict__ hdr,
                                                    int vbase) {
    __shared__ int U[UF_LDS];                // 60 KB
    __shared__ int sred[16];
    int vloc = blockIdx.x;
    int v = vbase + vloc;
    int R = hdr[H_RIDB(v)];
    const unsigned long long* E = edges + (size_t)vloc * EDGE_CAP;
    const int* C = counts + vloc * EDGE_SLICES;

    int ev = 0;
    if (R <= UF_LDS) {
        for (int i = threadIdx.x; i < R; i += 1024) U[i] = i;
        __syncthreads();
        for (int e = threadIdx.x; e < EDGE_CAP; e += 1024) {
            if ((e & 31) < C[e >> 5]) {
                unsigned long long k = E[e];
                int a = find_ro(U, (int)(k >> 32));
                int b = find_ro(U, (int)(unsigned)k);
                if (a != b) ev += merge_count(U, a, b);
            }
        }
    } else {
        int* Ug = UFg + (size_t)vloc * MAXR;
        for (int i = threadIdx.x; i < R; i += 1024) Ug[i] = i;
        __syncthreads();
        for (int e = threadIdx.x; e < EDGE_CAP; e += 1024) {
            if ((e & 31) < C[e >> 5]) {
                unsigned long long k = E[e];
                int a = find_ro(Ug, (int)(k >> 32));
                int b = find_ro(Ug, (int)(unsigned)k);
                if (a != b) ev += merge_count(Ug, a, b);
            }
        }
    }
    for (int off = 32; off; off >>= 1) ev += __shfl_down(ev, off, 64);
    if ((threadIdx.x & 63) == 0) sred[threadIdx.x >> 6] = ev;
    __syncthreads();
    if (threadIdx.x == 0) {
        int t = 0;
        for (int w = 0; w < 16; w++) t += sred[w];
        hdr[H_EVT(v)] = t;
    }
}

// ---------------------------------------------------------------------------
__global__ void finalize_kernel(const int* __restrict__ hdr,
                                float* __restrict__ out) {
    float focal = ((const float*)hdr)[H_ACC] / (float)NEL;
    float c[NVOL];
    for (int v = 0; v < NVOL; v++)
        c[v] = (float)(hdr[H_ROOT(v)] - hdr[H_EVT(v)]);
    float dp0 = 0.5f * (c[0] + c[2]);
    float dp1 = 0.5f * (c[1] + c[3]);
    float dt0 = 0.5f * (c[4] + c[6]);
    float dt1 = 0.5f * (c[5] + c[7]);
    float topo = 0.5f * (fabsf(dp0 - dt0) + fabsf(dp1 - dt1));
    out[0] = focal + 0.1f * topo;
}

// ---------------------------------------------------------------------------
extern "C" void kernel_launch(void* const* d_in, const int* in_sizes, int n_in,
                              void* d_out, int out_size, void* d_ws, size_t ws_size,
                              hipStream_t stream) {
    const float* pred = (const float*)d_in[0];
    const float* targ = (const float*)d_in[1];
    float* out = (float*)d_out;

    int* hdr = (int*)d_ws;
    char* body = (char*)d_ws + HDR_BYTES;

    // body: edges[vp*EDGE_CAP] u64 | UF[vp*MAXR] | faces[vp*FACES_PER_VOL] |
    //       counts[vp*EDGE_SLICES]
    size_t per_vol = 2 * (size_t)EDGE_CAP + MAXR + FACES_PER_VOL + EDGE_SLICES;
    size_t avail_ints = (ws_size > HDR_BYTES) ? (ws_size - HDR_BYTES) / 4 : 0;
    int vols_per_pass = (int)(avail_ints / per_vol);
    if (vols_per_pass > NVOL) vols_per_pass = NVOL;
    if (vols_per_pass < 1) vols_per_pass = 1;

    unsigned long long* edges = (unsigned long long*)body;
    int* UF     = (int*)(edges + (size_t)vols_per_pass * EDGE_CAP);
    int* faces  = UF + (size_t)vols_per_pass * MAXR;
    int* counts = faces + (size_t)vols_per_pass * FACES_PER_VOL;

    hipMemsetAsync(d_ws, 0, HDR_BYTES, stream);

    for (int vbase = 0; vbase < NVOL; vbase += vols_per_pass) {
        int nv = NVOL - vbase;
        if (nv > vols_per_pass) nv = vols_per_pass;
        dim3 tgrid(TILES_W * TILES_H, nv);
        ccl_local<<<tgrid, dim3(256), 0, stream>>>(pred, targ, faces, hdr, vbase);
        dim3 bgrid(BOUND_VOX / 256, nv);
        ccl_boundary<<<bgrid, dim3(256), 0, stream>>>(faces, edges, counts, vbase);
        ccl_resolve<<<dim3(nv), dim3(1024), 0, stream>>>(UF, edges, counts, hdr, vbase);
    }

    finalize_kernel<<<1, 1, 0, stream>>>(hdr, out);
}

// Round 13
// 234.444 us; speedup vs baseline: 2.8674x; 1.0196x over previous
//
#include <hip/hip_runtime.h>
#include <math.h>
#include <limits.h>

#define N_VOX (96*96*96)        // 884736 voxels per volume
#define NVOL 8                  // 4 pred + 4 target volumes
#define NEL (4*N_VOX)           // 3538944 elements in pred/target
#define PLANE (96*96)           // 9216

#define TW 8
#define TH 8
#define TILES_W 12
#define TILES_H 12
#define TILE_VOX (96*TW*TH)     // 6144
#define TILE_WORDS (TILE_VOX/32) // 192

#define NBPLANES 11
#define BOUND_VOX (2*NBPLANES*PLANE)       // 202752 = 792*256
#define FACES_PER_VOL (2*2*NBPLANES*PLANE) // 405504 ints
#define MAXR (144*1536)                    // worst-case boundary roots/volume
#define EDGE_SLICES (792*4)                // one 32-slot slice per wave
#define EDGE_CAP (EDGE_SLICES*32)          // 101376 u64 per volume
#define UF_LDS 15360                       // LDS union-find capacity (60 KB)

// header: padded counters, one 128-B line each (int offsets)
#define HDR_BYTES 4096
#define H_ACC 0                  // float, line 0
#define H_ROOT(v) (32*(1+(v)))   // total roots, lines 1..8
#define H_EVT(v)  (32*(9+(v)))   // union events, lines 9..16
#define H_RIDB(v) (32*(17+(v)))  // boundary-rid allocator, lines 17..24

// ---------------------------------------------------------------------------
// find with CONDITIONAL path compression: write only when the walk was >= 2
// hops. Duplicate edges (the majority) then cost 2 LDS reads and ZERO
// atomics, while deep chains get flattened exactly once. This fixes both
// r11's atomic storm (unconditional write per find) and r12's deep-chain
// latency (no compression at all, ~120cyc per dependent LDS hop).
__device__ __forceinline__ int find_cc(int* __restrict__ L, int x) {
    int p = L[x];
    if (p == x) return x;
    int r = p, q = L[r];
    while (q != r) { r = q; q = L[r]; }
    if (p != r) atomicMin(&L[x], r);   // monotone decrease: r <= all on chain
    return r;
}

// atomicMin union-find merge; returns # destroyed self-loops (union events).
__device__ __forceinline__ int merge_count(int* __restrict__ L, int l1, int l2) {
    int ev = 0;
    while (l1 != l2) {
        if (l1 < l2) { int t = l1; l1 = l2; l2 = t; }   // l1 > l2
        int l3 = atomicMin(&L[l1], l2);
        if (l3 == l1) { ev++; l1 = l2; }
        else l1 = l3;
    }
    return ev;
}

__device__ __forceinline__ void merge_local(int* lab, int l1, int l2) {
    while (l1 != l2 && l1 != lab[l1]) l1 = lab[l1];
    while (l1 != l2 && l2 != lab[l2]) l2 = lab[l2];
    while (l1 != l2) {
        if (l1 < l2) { int t = l1; l1 = l2; l2 = t; }
        int l3 = atomicMin(&lab[l1], l2);
        l1 = (l3 == l1) ? l2 : l3;
    }
}

__device__ __forceinline__ int run_start(const unsigned* fm, int i, int d) {
    int rowb = (i - d) >> 5;
    int k = d >> 5, bit = d & 31;
    unsigned below = bit ? (~fm[rowb + k] & ((1u << bit) - 1)) : 0u;
    int z = -1;
    if (below) z = (k << 5) + 31 - __builtin_clz(below);
    else if (k > 0) {
        unsigned n1 = ~fm[rowb + k - 1];
        if (n1) z = ((k - 1) << 5) + 31 - __builtin_clz(n1);
        else if (k > 1) {
            unsigned n0 = ~fm[rowb];
            if (n0) z = 31 - __builtin_clz(n0);
        }
    }
    return (i - d) + z + 1;
}

// ---------------------------------------------------------------------------
// Phase 1: run-based per-tile CCL in LDS. Face-touching roots get compact
// boundary ids (UF space); interior roots are only counted. Faces store
// resolved boundary rids (-1 = bg). Focal partial fused.
__global__ __launch_bounds__(256) void ccl_local(const float* __restrict__ pred,
                                                 const float* __restrict__ targ,
                                                 int* __restrict__ faces,
                                                 int* __restrict__ hdr,
                                                 int vbase) {
    __shared__ int lab[TILE_VOX];
    __shared__ unsigned fm[TILE_WORDS];
    __shared__ unsigned mark[TILE_WORDS];    // face-touching root bitmap
    __shared__ float fws[4];
    __shared__ int nb, ni;                   // boundary / interior root counts
    __shared__ int ridbase;

    int vloc = blockIdx.y;
    int v = vbase + vloc;
    int tile = blockIdx.x;
    int tw = tile % TILES_W, th = tile / TILES_W;
    int w0 = tw * TW, h0 = th * TH;
    int tbase = h0 * PLANE + w0 * 96;
    int* Fw  = faces + (size_t)vloc * FACES_PER_VOL;
    int* Fh  = Fw + 2 * NBPLANES * PLANE;
    if (threadIdx.x == 0) { nb = 0; ni = 0; }
    for (int t = threadIdx.x; t < TILE_WORDS; t += 256) mark[t] = 0u;

    float fsum = 0.0f;
    for (int it = 0; it < TILE_VOX / 256; it++) {
        int i = it * 256 + threadIdx.x;
        int lh = i / 768;
        int j = tbase + i + lh * 8448;
        bool f;
        if (v < 4) {
            float xv = pred[(size_t)v * N_VOX + j];
            float tv = targ[(size_t)v * N_VOX + j];
            f = xv > 0.0f;
            float m   = (tv == 1.0f) ? -xv : xv;
            float at  = (tv == 1.0f) ? 0.25f : 0.75f;
            float e   = __expf(-fabsf(m));
            float inv = 1.0f / (1.0f + e);
            float sig = inv * ((m >= 0.0f) ? 1.0f : e);
            float sp  = fmaxf(m, 0.0f) + __logf(1.0f + e);
            fsum += at * sig * sig * sp;
        } else {
            f = targ[(size_t)(v - 4) * N_VOX + j] > 0.5f;
        }
        unsigned long long bal = __ballot(f);
        if ((threadIdx.x & 63) == 0) {
            fm[i >> 5]       = (unsigned)bal;
            fm[(i >> 5) + 1] = (unsigned)(bal >> 32);
        }
        lab[i] = i;
    }
    __syncthreads();

    // intra-tile merges at overlap-segment starts
    for (int t = threadIdx.x; t < 336; t += 256) {
        bool wdir = t < 168;
        int tt = wdir ? t : t - 168;
        int lh, lw, k;
        if (wdir) { lh = tt / 21; int rem = tt % 21; lw = rem / 3; k = rem % 3; }
        else      { lh = tt / 24; int rem = tt % 24; lw = rem / 3; k = rem % 3; }
        int wb = (lh * 8 + lw) * 3 + k;
        int nbw = wb + (wdir ? 3 : 24);
        unsigned ov = fm[wb] & fm[nbw];
        if (!ov) continue;
        unsigned carry = (k > 0) ? ((fm[wb - 1] & fm[nbw - 1]) >> 31) : 0u;
        unsigned starts = ov & ~((ov << 1) | carry);
        int base_i = wb << 5;
        int dir = wdir ? 96 : 768;
        while (starts) {
            int b = __builtin_ctz(starts);
            starts &= starts - 1;
            int i = base_i + b;
            int d = (k << 5) + b;
            merge_local(lab, run_start(fm, i, d), run_start(fm, i + dir, d));
        }
    }
    __syncthreads();

    // M: mark roots of run-starts on the 4 stored faces
    for (int t = threadIdx.x; t < 96; t += 256) {
        int rowsel = t / 3, k = t % 3;
        int lh, lw;
        if (rowsel < 8)       { lh = rowsel;      lw = 0; }
        else if (rowsel < 16) { lh = rowsel - 8;  lw = 7; }
        else if (rowsel < 24) { lh = 0;           lw = rowsel - 16; }
        else                  { lh = 7;           lw = rowsel - 24; }
        int wb = (lh * 8 + lw) * 3 + k;
        unsigned m = fm[wb];
        if (!m) continue;
        unsigned carry = k ? (fm[wb - 1] >> 31) : 0u;
        unsigned starts = m & ~((m << 1) | carry);
        int base_i = wb << 5;
        while (starts) {
            int b = __builtin_ctz(starts); starts &= starts - 1;
            int r = base_i + b;
            while (lab[r] != r) r = lab[r];
            atomicOr(&mark[r >> 5], 1u << (r & 31));
        }
    }
    __syncthreads();

    // A1: marked roots get boundary rank enc=-2-rank; interior roots counted
    for (int t = threadIdx.x; t < TILE_WORDS; t += 256) {
        unsigned m = fm[t];
        if (!m) continue;
        unsigned carry = (t % 3) ? (fm[t - 1] >> 31) : 0u;
        unsigned starts = m & ~((m << 1) | carry);
        int base_i = t << 5;
        while (starts) {
            int b = __builtin_ctz(starts); starts &= starts - 1;
            int i = base_i + b;
            if (lab[i] == i) {
                if ((mark[i >> 5] >> (i & 31)) & 1) {
                    int rank = atomicAdd(&nb, 1);
                    lab[i] = -2 - rank;
                } else {
                    atomicAdd(&ni, 1);
                    lab[i] = INT_MIN;
                }
            }
        }
    }
    __syncthreads();

    // A2: non-root run-starts copy their root's enc (walk ends at <0)
    for (int t = threadIdx.x; t < TILE_WORDS; t += 256) {
        unsigned m = fm[t];
        if (!m) continue;
        unsigned carry = (t % 3) ? (fm[t - 1] >> 31) : 0u;
        unsigned starts = m & ~((m << 1) | carry);
        int base_i = t << 5;
        while (starts) {
            int b = __builtin_ctz(starts); starts &= starts - 1;
            int i = base_i + b;
            int p = lab[i];
            if (p >= 0) {
                int r = p; p = lab[r];
                while (p >= 0) { r = p; p = lab[r]; }
                lab[i] = p;
            }
        }
    }
    __syncthreads();

    if (threadIdx.x == 0) {
        ridbase = atomicAdd(&hdr[H_RIDB(v)], nb);
        atomicAdd(&hdr[H_ROOT(v)], nb + ni);
    }
    __syncthreads();
    int base = ridbase;

    // faces store (int4 groups); every enc read here is a boundary enc
    for (int t = threadIdx.x; t < 768; t += 256) {
        int f  = t / 192;
        int g  = t % 192;
        int u  = g / 24;
        int d4 = (g % 24) * 4;
        int i0; int* dst;
        if (f == 0) {
            if (tw == 0) continue;
            i0  = u * 768 + d4;
            dst = Fw + ((tw - 1) * 2 + 1) * PLANE + (h0 + u) * 96 + d4;
        } else if (f == 1) {
            if (tw == TILES_W - 1) continue;
            i0  = u * 768 + 7 * 96 + d4;
            dst = Fw + (tw * 2) * PLANE + (h0 + u) * 96 + d4;
        } else if (f == 2) {
            if (th == 0) continue;
            i0  = u * 96 + d4;
            dst = Fh + ((th - 1) * 2 + 1) * PLANE + (w0 + u) * 96 + d4;
        } else {
            if (th == TILES_H - 1) continue;
            i0  = 7 * 768 + u * 96 + d4;
            dst = Fh + (th * 2) * PLANE + (w0 + u) * 96 + d4;
        }
        unsigned mw = fm[i0 >> 5];
        int vals[4];
        bool prevf = false;
        for (int q = 0; q < 4; q++) {
            bool fb = (mw >> ((d4 & 31) + q)) & 1;
            if (fb) vals[q] = prevf ? vals[q - 1]
                                    : base - 2 - lab[run_start(fm, i0 + q, d4 + q)];
            else vals[q] = -1;
            prevf = fb;
        }
        *(int4*)dst = make_int4(vals[0], vals[1], vals[2], vals[3]);
    }

    if (v < 4) {
        for (int off = 32; off; off >>= 1) fsum += __shfl_down(fsum, off, 64);
        int wid = threadIdx.x >> 6;
        if ((threadIdx.x & 63) == 0) fws[wid] = fsum;
        __syncthreads();
        if (threadIdx.x == 0) {
            float ft = fws[0] + fws[1] + fws[2] + fws[3];
            if (ft != 0.0f) atomicAdd((float*)&hdr[H_ACC], ft);
        }
    }
}

// ---------------------------------------------------------------------------
// Phase 2: pure edge extraction, ZERO global atomics.
__global__ __launch_bounds__(256) void ccl_boundary(const int* __restrict__ faces,
                                                    unsigned long long* __restrict__ edges,
                                                    int* __restrict__ counts,
                                                    int vbase) {
    int tid  = blockIdx.x * 256 + threadIdx.x;   // < BOUND_VOX
    int vloc = blockIdx.y;
    const int* F = faces + (size_t)vloc * FACES_PER_VOL;

    int face = tid / PLANE;
    int e    = tid % PLANE;
    const int* A;
    const int* B;
    if (face < NBPLANES) {
        A = F + (face * 2) * PLANE;
        B = F + (face * 2 + 1) * PLANE;
    } else {
        const int* Fh = F + 2 * NBPLANES * PLANE;
        int b = face - NBPLANES;
        A = Fh + (b * 2) * PLANE;
        B = Fh + (b * 2 + 1) * PLANE;
    }

    int a = A[e], b2 = B[e];
    bool want = false;
    unsigned long long key = 0;
    if (a >= 0 && b2 >= 0) {
        int d = e % 96;
        if (d == 0 || A[e - 1] < 0 || B[e - 1] < 0) {   // segment start
            int rmin = a < b2 ? a : b2;
            int rmax = a < b2 ? b2 : a;
            key = ((unsigned long long)rmin << 32) | (unsigned)rmax;
            want = true;
        }
    }

    int lane = threadIdx.x & 63;
    unsigned long long m0 = __ballot(want);
    unsigned long long kup = __shfl_up(key, 1, 64);
    if (want && lane > 0 && ((m0 >> (lane - 1)) & 1) && kup == key) want = false;
    unsigned long long mask = __ballot(want);

    int slice = blockIdx.x * 4 + (threadIdx.x >> 6);
    if (lane == 0) counts[vloc * EDGE_SLICES + slice] = (int)__popcll(mask);
    if (want) {
        int rank = (int)__popcll(mask & ((1ull << lane) - 1));
        edges[(size_t)vloc * EDGE_CAP + slice * 32 + rank] = key;
    }
}

// ---------------------------------------------------------------------------
// Phase 3: one block per volume; union-find in LDS with conditional path
// compression (find_cc). Duplicate edges cost 2 LDS reads, no atomics;
// deep chains are flattened exactly once.
__global__ __launch_bounds__(1024) void ccl_resolve(int* __restrict__ UFg,
                                                    const unsigned long long* __restrict__ edges,
                                                    const int* __restrict__ counts,
                                                    int* __restrict__ hdr,
                                                    int vbase) {
    __shared__ int U[UF_LDS];                // 60 KB
    __shared__ int sred[16];
    int vloc = blockIdx.x;
    int v = vbase + vloc;
    int R = hdr[H_RIDB(v)];
    const unsigned long long* E = edges + (size_t)vloc * EDGE_CAP;
    const int* C = counts + vloc * EDGE_SLICES;

    int ev = 0;
    if (R <= UF_LDS) {
        for (int i = threadIdx.x; i < R; i += 1024) U[i] = i;
        __syncthreads();
        for (int e = threadIdx.x; e < EDGE_CAP; e += 1024) {
            if ((e & 31) < C[e >> 5]) {
                unsigned long long k = E[e];
                int a = find_cc(U, (int)(k >> 32));
                int b = find_cc(U, (int)(unsigned)k);
                if (a != b) ev += merge_count(U, a, b);
            }
        }
    } else {
        int* Ug = UFg + (size_t)vloc * MAXR;
        for (int i = threadIdx.x; i < R; i += 1024) Ug[i] = i;
        __syncthreads();
        for (int e = threadIdx.x; e < EDGE_CAP; e += 1024) {
            if ((e & 31) < C[e >> 5]) {
                unsigned long long k = E[e];
                int a = find_cc(Ug, (int)(k >> 32));
                int b = find_cc(Ug, (int)(unsigned)k);
                if (a != b) ev += merge_count(Ug, a, b);
            }
        }
    }
    for (int off = 32; off; off >>= 1) ev += __shfl_down(ev, off, 64);
    if ((threadIdx.x & 63) == 0) sred[threadIdx.x >> 6] = ev;
    __syncthreads();
    if (threadIdx.x == 0) {
        int t = 0;
        for (int w = 0; w < 16; w++) t += sred[w];
        hdr[H_EVT(v)] = t;
    }
}

// ---------------------------------------------------------------------------
__global__ void finalize_kernel(const int* __restrict__ hdr,
                                float* __restrict__ out) {
    float focal = ((const float*)hdr)[H_ACC] / (float)NEL;
    float c[NVOL];
    for (int v = 0; v < NVOL; v++)
        c[v] = (float)(hdr[H_ROOT(v)] - hdr[H_EVT(v)]);
    float dp0 = 0.5f * (c[0] + c[2]);
    float dp1 = 0.5f * (c[1] + c[3]);
    float dt0 = 0.5f * (c[4] + c[6]);
    float dt1 = 0.5f * (c[5] + c[7]);
    float topo = 0.5f * (fabsf(dp0 - dt0) + fabsf(dp1 - dt1));
    out[0] = focal + 0.1f * topo;
}

// ---------------------------------------------------------------------------
extern "C" void kernel_launch(void* const* d_in, const int* in_sizes, int n_in,
                              void* d_out, int out_size, void* d_ws, size_t ws_size,
                              hipStream_t stream) {
    const float* pred = (const float*)d_in[0];
    const float* targ = (const float*)d_in[1];
    float* out = (float*)d_out;

    int* hdr = (int*)d_ws;
    char* body = (char*)d_ws + HDR_BYTES;

    // body: edges[vp*EDGE_CAP] u64 | UF[vp*MAXR] | faces[vp*FACES_PER_VOL] |
    //       counts[vp*EDGE_SLICES]
    size_t per_vol = 2 * (size_t)EDGE_CAP + MAXR + FACES_PER_VOL + EDGE_SLICES;
    size_t avail_ints = (ws_size > HDR_BYTES) ? (ws_size - HDR_BYTES) / 4 : 0;
    int vols_per_pass = (int)(avail_ints / per_vol);
    if (vols_per_pass > NVOL) vols_per_pass = NVOL;
    if (vols_per_pass < 1) vols_per_pass = 1;

    unsigned long long* edges = (unsigned long long*)body;
    int* UF     = (int*)(edges + (size_t)vols_per_pass * EDGE_CAP);
    int* faces  = UF + (size_t)vols_per_pass * MAXR;
    int* counts = faces + (size_t)vols_per_pass * FACES_PER_VOL;

    hipMemsetAsync(d_ws, 0, HDR_BYTES, stream);

    for (int vbase = 0; vbase < NVOL; vbase += vols_per_pass) {
        int nv = NVOL - vbase;
        if (nv > vols_per_pass) nv = vols_per_pass;
        dim3 tgrid(TILES_W * TILES_H, nv);
        ccl_local<<<tgrid, dim3(256), 0, stream>>>(pred, targ, faces, hdr, vbase);
        dim3 bgrid(BOUND_VOX / 256, nv);
        ccl_boundary<<<bgrid, dim3(256), 0, stream>>>(faces, edges, counts, vbase);
        ccl_resolve<<<dim3(nv), dim3(1024), 0, stream>>>(UF, edges, counts, hdr, vbase);
    }

    finalize_kernel<<<1, 1, 0, stream>>>(hdr, out);
}